// Round 6
// baseline (116.530 us; speedup 1.0000x reference)
//
#include <hip/hip_runtime.h>
#include <hip/hip_bf16.h>

#define B_ 64
#define L_ 512
#define H_ 1024
#define EPS_ 1e-13f

typedef unsigned short u16;
typedef __attribute__((ext_vector_type(8))) short s16x8;
typedef __attribute__((ext_vector_type(4))) float f32x4;

__device__ __forceinline__ u16 f2bf(float f) {
  __hip_bfloat16 h = __float2bfloat16(f);
  union { __hip_bfloat16 h; u16 u; } c; c.h = h; return c.u;
}

// ---- Kernel 1: row softmax + mask renorm -> W bf16. 4 rows/wave, loads batched
// up-front (128B/thread in flight), 4 reduction chains interleaved for ILP. ----
__global__ __launch_bounds__(256) void softmax_rows(const float* __restrict__ att,
                                                    const float* __restrict__ mask,
                                                    u16* __restrict__ Wout) {
  const int w = threadIdx.x >> 6, lane = threadIdx.x & 63;
  const int row0 = blockIdx.x * 16 + w * 4;

  float a[4][8];
#pragma unroll
  for (int r = 0; r < 4; ++r) {
    const float* p = att + (size_t)(row0 + r) * L_ + lane * 8;
    float4 v0 = *(const float4*)p;
    float4 v1 = *(const float4*)(p + 4);
    a[r][0] = v0.x; a[r][1] = v0.y; a[r][2] = v0.z; a[r][3] = v0.w;
    a[r][4] = v1.x; a[r][5] = v1.y; a[r][6] = v1.z; a[r][7] = v1.w;
  }

  float m[4];
#pragma unroll
  for (int r = 0; r < 4; ++r) {
    m[r] = a[r][0];
#pragma unroll
    for (int j = 1; j < 8; ++j) m[r] = fmaxf(m[r], a[r][j]);
  }
#pragma unroll
  for (int off = 32; off > 0; off >>= 1)
#pragma unroll
    for (int r = 0; r < 4; ++r) m[r] = fmaxf(m[r], __shfl_xor(m[r], off));

  float z[4] = {0.f, 0.f, 0.f, 0.f};
#pragma unroll
  for (int r = 0; r < 4; ++r)
#pragma unroll
    for (int j = 0; j < 8; ++j) { a[r][j] = __expf(a[r][j] - m[r]); z[r] += a[r][j]; }
#pragma unroll
  for (int off = 32; off > 0; off >>= 1)
#pragma unroll
    for (int r = 0; r < 4; ++r) z[r] += __shfl_xor(z[r], off);

#pragma unroll
  for (int r = 0; r < 4; ++r) {
    const float mk = mask[row0 + r];
    const float c = (1.0f / z[r]) * (mk / (mk + EPS_));  // softmax row-sum == 1
    union { u16 u[8]; uint4 v; } wv;
#pragma unroll
    for (int j = 0; j < 8; ++j) wv.u[j] = f2bf(a[r][j] * c);
    *(uint4*)(Wout + (size_t)(row0 + r) * L_ + lane * 8) = wv.v;
  }
}

// ---- Kernel 2: transpose+convert X f32 [B,L,H] -> XT bf16 [B,H,L] ----
// (round-3 proven structure: <=2-way LDS banks, 128B write segments)
__global__ __launch_bounds__(256) void transpose_x(const float* __restrict__ X,
                                                   u16* __restrict__ XT) {
  const int bid = blockIdx.x;
  const int lt = bid & 7;          // L/64
  const int ht = (bid >> 3) & 15;  // H/64
  const int b  = bid >> 7;
  const int l0 = lt * 64, h0 = ht * 64;

  __shared__ __align__(16) u16 tile[64 * 64];
  const int t = threadIdx.x;
  const int cg = t & 7;
  const int rr = t >> 3;

#pragma unroll
  for (int it = 0; it < 2; ++it) {
    int r = rr + it * 32;
    size_t gidx = ((size_t)(b * L_ + l0 + r)) * H_ + h0 + cg * 8;
    float4 u0 = *(const float4*)(X + gidx);
    float4 u1 = *(const float4*)(X + gidx + 4);
    union { u16 u[8]; uint4 v; } w;
    w.u[0] = f2bf(u0.x); w.u[1] = f2bf(u0.y); w.u[2] = f2bf(u0.z); w.u[3] = f2bf(u0.w);
    w.u[4] = f2bf(u1.x); w.u[5] = f2bf(u1.y); w.u[6] = f2bf(u1.z); w.u[7] = f2bf(u1.w);
    int g = cg ^ (r & 7) ^ ((r >> 3) & 7);
    *(uint4*)&tile[r * 64 + g * 8] = w.v;
  }
  __syncthreads();
#pragma unroll
  for (int it = 0; it < 2; ++it) {
    int hc = rr + it * 32;
    union { u16 u[8]; uint4 v; } e;
#pragma unroll
    for (int m2 = 0; m2 < 8; ++m2) {
      int r = cg * 8 + m2;
      int g = (hc >> 3) ^ (r & 7) ^ ((r >> 3) & 7);
      e.u[m2] = tile[r * 64 + g * 8 + (hc & 7)];
    }
    *(uint4*)(XT + ((size_t)(b * H_ + h0 + hc)) * L_ + l0 + cg * 8) = e.v;
  }
}

#define GLOAD(gp, lp)                                                              \
  __builtin_amdgcn_global_load_lds((const __attribute__((address_space(1))) unsigned*)(gp), \
                                   (__attribute__((address_space(3))) unsigned*)(void*)(lp), 16, 0, 0)

// ---- Kernel 3: batched GEMM out = W @ X via XT. 256x256 tile, 8 waves.
// Deep pipeline: BK=32, 4-region LDS ring, depth-3 prefetch, counted vmcnt(8),
// setprio around MFMA, 2-way-max XOR swizzle. (unchanged from round 5, ~25 us)
__global__ __launch_bounds__(512, 2) void gemm_bt(const u16* __restrict__ Wm,
                                                  const u16* __restrict__ XT,
                                                  float* __restrict__ out) {
  const int K = L_;     // 512
  const int NT = 16;    // K / 32
  const int swz = (blockIdx.x & 7) * 64 + (blockIdx.x >> 3);
  const int b  = swz >> 3;
  const int mt = (swz >> 2) & 1;
  const int nt = swz & 3;

  __shared__ __align__(16) char lds[4 * 32768];  // region: A 16KB @+0, B 16KB @+16384

  const int t = threadIdx.x;
  const int lane = t & 63;
  const int w = t >> 6;
  const int wm = w >> 2, wn = w & 3;  // 2x4 waves, 128x64 out each

  const u16* gA = Wm + ((size_t)b * L_ + mt * 256) * K;
  const u16* gB = XT + ((size_t)b * H_ + nt * 256) * K;

  const int r0 = t >> 2;
  const int xsw = ((r0 & 3) ^ ((r0 >> 2) & 3));
  const int scol = ((t & 3) ^ xsw) * 8;
  const u16* pA0 = gA + (size_t)r0 * K + scol;
  const u16* pB0 = gB + (size_t)r0 * K + scol;
  char* dA = lds + w * 1024;
  char* dB = lds + 16384 + w * 1024;

  int offA[8], offB[4];
#pragma unroll
  for (int mf = 0; mf < 8; ++mf) {
    int r = wm * 128 + mf * 16 + (lane & 15);
    offA[mf] = r * 64 + ((((lane >> 4) ^ (r & 3) ^ ((r >> 2) & 3))) << 4);
  }
#pragma unroll
  for (int nf = 0; nf < 4; ++nf) {
    int r = wn * 64 + nf * 16 + (lane & 15);
    offB[nf] = 16384 + r * 64 + ((((lane >> 4) ^ (r & 3) ^ ((r >> 2) & 3))) << 4);
  }

  f32x4 acc[8][4] = {};

#define STAGE(tt)                                                  \
  do {                                                             \
    const int _rg = (tt) & 3;                                      \
    const int _kt = (tt) * 32;                                     \
    GLOAD(pA0 + _kt, dA + _rg * 32768);                            \
    GLOAD(pA0 + _kt + 128 * K, dA + _rg * 32768 + 8192);           \
    GLOAD(pB0 + _kt, dB + _rg * 32768);                            \
    GLOAD(pB0 + _kt + 128 * K, dB + _rg * 32768 + 8192);           \
  } while (0)

  STAGE(0); STAGE(1); STAGE(2);
  asm volatile("s_waitcnt vmcnt(8)" ::: "memory");
  __builtin_amdgcn_s_barrier();

#pragma unroll
  for (int k = 0; k < NT; ++k) {
    if (k + 3 < NT) STAGE(k + 3);

    const char* base = lds + (k & 3) * 32768;
    s16x8 af[8], bf4[4];
#pragma unroll
    for (int mf = 0; mf < 8; ++mf) af[mf] = *(const s16x8*)(base + offA[mf]);
#pragma unroll
    for (int nf = 0; nf < 4; ++nf) bf4[nf] = *(const s16x8*)(base + offB[nf]);
    asm volatile("s_waitcnt lgkmcnt(0)" ::: "memory");

    __builtin_amdgcn_s_setprio(1);
#pragma unroll
    for (int mf = 0; mf < 8; ++mf)
#pragma unroll
      for (int nf = 0; nf < 4; ++nf)
        acc[mf][nf] = __builtin_amdgcn_mfma_f32_16x16x32_bf16(af[mf], bf4[nf], acc[mf][nf], 0, 0, 0);
    __builtin_amdgcn_s_setprio(0);

    if (k < NT - 3)       asm volatile("s_waitcnt vmcnt(8)" ::: "memory");
    else if (k == NT - 3) asm volatile("s_waitcnt vmcnt(4)" ::: "memory");
    else if (k == NT - 2) asm volatile("s_waitcnt vmcnt(0)" ::: "memory");
    if (k < NT - 1) __builtin_amdgcn_s_barrier();
  }
#undef STAGE

  const int orow0 = mt * 256 + wm * 128 + ((lane >> 4) << 2);
  const int ocol0 = nt * 256 + wn * 64 + (lane & 15);
#pragma unroll
  for (int mf = 0; mf < 8; ++mf)
#pragma unroll
    for (int nf = 0; nf < 4; ++nf)
#pragma unroll
      for (int j = 0; j < 4; ++j) {
        int row = orow0 + mf * 16 + j;
        int col = ocol0 + nf * 16;
        out[((size_t)b * L_ + row) * H_ + col] = acc[mf][nf][j];
      }
}

extern "C" void kernel_launch(void* const* d_in, const int* in_sizes, int n_in,
                              void* d_out, int out_size, void* d_ws, size_t ws_size,
                              hipStream_t stream) {
  (void)in_sizes; (void)n_in; (void)out_size; (void)ws_size;
  const float* sent = (const float*)d_in[0];  // [B, L, H] f32
  const float* mask = (const float*)d_in[1];  // [B, L]    f32
  const float* att  = (const float*)d_in[2];  // [B, L, L] f32
  u16* Wm = (u16*)d_ws;                       // [B, L, L] bf16 (32 MiB)
  u16* XT = Wm + (size_t)B_ * L_ * L_;        // [B, H, L] bf16 (64 MiB)
  float* outp = (float*)d_out;                // [B, L, H] f32

  softmax_rows<<<2048, 256, 0, stream>>>(att, mask, Wm);
  transpose_x<<<B_ * (H_ / 64) * (L_ / 64), 256, 0, stream>>>(sent, XT);
  gemm_bt<<<B_ * 2 * 4, 512, 0, stream>>>(Wm, XT, outp);
}